// Round 1
// baseline (468.813 us; speedup 1.0000x reference)
//
#include <hip/hip_runtime.h>
#include <stdint.h>

// LSTM cell, fp32 I/O: z = x@Wx + h@Wh + bx + bh (M=32768, N=2048, K=1024)
// fused with gate activations and C/h update. bf16 MFMA, fp32 accumulate.
// R5: 256x256 8-phase schedule (HK-style T3+T4+T5):
//     - BM=BN=256, BK=64, 8 waves (2Mx4N), 128 KiB dbuf LDS, 1 block/CU
//     - per phase: ds_read subtile || global_load_lds issue -> raw s_barrier
//       -> lgkmcnt(0) -> setprio(1) 16xMFMA setprio(0) -> raw s_barrier
//     - counted vmcnt: tile t+1 issued during t's ph1-3; ph4 vmcnt(0) is an
//       exact drain with ~2 phases of slack (no younger loads outstanding)
//     - pack_w layout reused: p = q*256+wn*64+cn*16+l -> gate=cn,
//       hd=q*64+wn*16+l, so fused epilogue keeps all 4 gates per wave
//     - non-temporal output stores (keep xh+C in L3; fixes 306MB fetch)

#define BROWS 32768
#define DH 512
#define KTOT 1024   // D_IN + D_H
#define BM 128
#define BK 64

typedef __attribute__((ext_vector_type(8))) __bf16 bf16x8;
typedef __attribute__((ext_vector_type(4))) float f32x4;
typedef __attribute__((address_space(1))) void gvoid;
typedef __attribute__((address_space(3))) void lvoid;

__device__ __forceinline__ void gl_lds16(const void* g, void* l) {
  __builtin_amdgcn_global_load_lds((gvoid*)g, (lvoid*)l, 16, 0, 0);
}

__device__ __forceinline__ float sigf(float v)  { return 1.0f / (1.0f + __expf(-v)); }
__device__ __forceinline__ float tanhf_(float v){ return 1.0f - 2.0f / (1.0f + __expf(2.0f * v)); }

// ---- pre-pass: xh[r][c] = bf16(c<512 ? x[r][c] : h[r][c-512]), coalesced ----
__global__ void conv_xh(const float* __restrict__ x, const float* __restrict__ h,
                        __bf16* __restrict__ xh) {
  int o = blockIdx.x * 256 + threadIdx.x;       // chunk of 8 elems
  int c = (o & 127) * 8;
  int r = o >> 7;
  const float* src = (c < DH) ? (x + (size_t)r * DH + c)
                              : (h + (size_t)r * DH + (c - DH));
  float4 f0 = *(const float4*)src;
  float4 f1 = *(const float4*)(src + 4);
  bf16x8 v;
  v[0] = (__bf16)f0.x; v[1] = (__bf16)f0.y; v[2] = (__bf16)f0.z; v[3] = (__bf16)f0.w;
  v[4] = (__bf16)f1.x; v[5] = (__bf16)f1.y; v[6] = (__bf16)f1.z; v[7] = (__bf16)f1.w;
  *(bf16x8*)(xh + (size_t)o * 8) = v;
}

// ---- pack: Wt[(jb*128+r)*1024+k], r = (hl>>4)*64 + g*16 + (hl&15),
//      n = g*512 + jb*32 + hl. Coalesced via LDS transpose tile.
//      NOTE: for a 256-wide block q this same layout reads as
//      p = q*256 + w*64 + g*16 + l  <->  n = g*512 + q*64 + w*16 + l. ----
__global__ void pack_w(const float* __restrict__ Wx, const float* __restrict__ Wh,
                       __bf16* __restrict__ Wt) {
  __shared__ __bf16 T[128][72];                 // +8 pad
  const int jb = blockIdx.y;
  const int k0 = blockIdx.x * 64;
  const float* Wsrc = (k0 < DH) ? (Wx + (size_t)k0 * 4 * DH)
                                : (Wh + (size_t)(k0 - DH) * 4 * DH);
  const int t = threadIdx.x;
  const int s = t & 31, kr0 = t >> 5;           // 32 seg-threads x 8 k-rows
  const int g = s >> 3, q = s & 7;
  const int r0 = (q >> 2) * 64 + g * 16 + (q & 3) * 4;
  #pragma unroll
  for (int it = 0; it < 8; ++it) {
    int kr = it * 8 + kr0;
    float4 f = *(const float4*)(Wsrc + (size_t)kr * 4 * DH + g * DH + jb * 32 + q * 4);
    T[r0 + 0][kr] = (__bf16)f.x;
    T[r0 + 1][kr] = (__bf16)f.y;
    T[r0 + 2][kr] = (__bf16)f.z;
    T[r0 + 3][kr] = (__bf16)f.w;
  }
  __syncthreads();
  #pragma unroll
  for (int it = 0; it < 4; ++it) {
    int lin = it * 256 + t;                     // 0..1023
    int r = lin >> 3, k8 = lin & 7;
    bf16x8 v;
    #pragma unroll
    for (int j = 0; j < 8; ++j) v[j] = T[r][k8 * 8 + j];
    *(bf16x8*)(Wt + (size_t)(jb * 128 + r) * KTOT + k0 + k8 * 8) = v;
  }
}

// ==== main fused GEMM: 256x256 8-phase ====
#define SB __builtin_amdgcn_sched_barrier(0)
#define PH_PRE do { SB; __builtin_amdgcn_s_barrier(); \
  asm volatile("s_waitcnt lgkmcnt(0)" ::: "memory"); SB; } while (0)
#define PH_POST do { SB; __builtin_amdgcn_s_barrier(); SB; } while (0)
#define PH_POST_VM do { SB; asm volatile("s_waitcnt vmcnt(0)" ::: "memory"); \
  __builtin_amdgcn_s_barrier(); SB; } while (0)

#define STAGE_A4(PN_, kk_) do { \
  _Pragma("unroll") \
  for (int s_ = 0; s_ < 4; ++s_) { \
    const int r_ = s_ * 64 + sr; \
    gl_lds16(xh + (size_t)(row0 + r_) * KTOT + (kk_) + cs8 * 8, \
             &As[PN_][(s_ * 512 + tid) * 8]); \
  } } while (0)

#define STAGE_B2(PN_, kk_, h_) do { \
  _Pragma("unroll") \
  for (int s_ = 2 * (h_); s_ < 2 * (h_) + 2; ++s_) { \
    const int r_ = s_ * 64 + sr; \
    gl_lds16(Bt + (size_t)r_ * KTOT + (kk_) + cs8 * 8, \
             &Bs[PN_][(s_ * 512 + tid) * 8]); \
  } } while (0)

#define DS_A4(P_, cmb_, ks_) do { \
  const int cc_ = ((ks_) * 4 + q) ^ (l15 & 7); \
  _Pragma("unroll") \
  for (int i_ = 0; i_ < 4; ++i_) { \
    const int row_ = wm * 128 + ((cmb_) + i_) * 16 + l15; \
    af[i_] = *(const bf16x8*)&As[P_][row_ * 64 + cc_ * 8]; \
  } } while (0)

#define DS_B4(P_, ks_) do { \
  const int cc_ = ((ks_) * 4 + q) ^ (l15 & 7); \
  _Pragma("unroll") \
  for (int i_ = 0; i_ < 4; ++i_) { \
    const int row_ = wn * 64 + i_ * 16 + l15; \
    bfr[i_] = *(const bf16x8*)&Bs[P_][row_ * 64 + cc_ * 8]; \
  } } while (0)

#define MFMA16(cmb_) do { \
  __builtin_amdgcn_s_setprio(1); \
  _Pragma("unroll") \
  for (int i_ = 0; i_ < 4; ++i_) \
    _Pragma("unroll") \
    for (int j_ = 0; j_ < 4; ++j_) \
      acc[(cmb_) + i_][j_] = __builtin_amdgcn_mfma_f32_16x16x32_bf16( \
          af[i_], bfr[j_], acc[(cmb_) + i_][j_], 0, 0, 0); \
  __builtin_amdgcn_s_setprio(0); \
} while (0)

// One K-tile = 4 phases. Reads buf P_, stages next tile into buf PN_.
#define TILE(T_, P_, PN_, DOST_) do { \
  bf16x8 af[4], bfr[4]; \
  /* ph1: B(ks0)+A(cm0-3,ks0); stage A(next), 4 issues */ \
  DS_B4(P_, 0); DS_A4(P_, 0, 0); \
  if (DOST_) STAGE_A4(PN_, ((T_) + 1) * BK); \
  PH_PRE; MFMA16(0); PH_POST; \
  /* ph2: A(cm4-7,ks0); stage B half0 */ \
  DS_A4(P_, 4, 0); \
  if (DOST_) STAGE_B2(PN_, ((T_) + 1) * BK, 0); \
  PH_PRE; MFMA16(4); PH_POST; \
  /* ph3: B(ks1)+A(cm0-3,ks1); stage B half1 */ \
  DS_B4(P_, 1); DS_A4(P_, 0, 1); \
  if (DOST_) STAGE_B2(PN_, ((T_) + 1) * BK, 1); \
  PH_PRE; MFMA16(0); PH_POST; \
  /* ph4: A(cm4-7,ks1); exact vmcnt drain of next tile's 8 loads */ \
  DS_A4(P_, 4, 1); \
  PH_PRE; MFMA16(4); PH_POST_VM; \
} while (0)

__global__ __launch_bounds__(512, 2) void lstm_gemm3(
    const __bf16* __restrict__ xh, const __bf16* __restrict__ Wt,
    const float* __restrict__ bx, const float* __restrict__ bh,
    const float* __restrict__ Cin, float* __restrict__ out) {
  __shared__ __attribute__((aligned(16))) __bf16 As[2][256 * 64];
  __shared__ __attribute__((aligned(16))) __bf16 Bs[2][256 * 64];

  const int tid  = threadIdx.x;
  const int lane = tid & 63;
  const int wave = tid >> 6;
  const int wm = wave >> 2, wn = wave & 3;      // 2M x 4N
  const int q = lane >> 4, l15 = lane & 15;
  const int jb   = blockIdx.x;                  // 0..7 -> XCD-pinned (idx%8)
  const int row0 = blockIdx.y * 256;

  const __bf16* Bt = Wt + (size_t)jb * 256 * KTOT;

  // per-thread staging geometry (constant across tiles)
  const int sr  = tid >> 3;                     // row within 64-row slot
  const int cs8 = (tid & 7) ^ (sr & 7);         // XOR chunk swizzle (T2)

  // bias prefetch; gate g = cn, hd = jb*64 + wn*16 + l
  const int hd = jb * 64 + wn * 16 + l15;
  float bias[4];
  #pragma unroll
  for (int g = 0; g < 4; ++g) bias[g] = bx[g * DH + hd] + bh[g * DH + hd];

  f32x4 acc[8][4];
  #pragma unroll
  for (int a_ = 0; a_ < 8; ++a_)
    #pragma unroll
    for (int b_ = 0; b_ < 4; ++b_) acc[a_][b_] = (f32x4)0.0f;

  // prologue: stage tile 0 -> buf0, tile 1 -> buf1; counted wait on tile 0
  STAGE_A4(0, 0); STAGE_B2(0, 0, 0); STAGE_B2(0, 0, 1);
  STAGE_A4(1, BK); STAGE_B2(1, BK, 0); STAGE_B2(1, BK, 1);
  asm volatile("s_waitcnt vmcnt(8)" ::: "memory");   // tile 0's 8 landed
  __builtin_amdgcn_s_barrier();

  // K loop: 16 tiles, unrolled by 2 for compile-time buffer indices.
  // Tile t's ph4 vmcnt(0) drains exactly tile t+1's stages (issued >= 2
  // phases earlier; nothing younger outstanding -> no over-drain).
  for (int tt = 0; tt < 16; tt += 2) {
    TILE(tt,     0, 1, (tt > 0));       // stages tt+1 (tile 1 pre-staged)
    TILE(tt + 1, 1, 0, (tt < 14));      // stages tt+2 into buf0 (t tt done)
  }

  // fused LSTM epilogue (non-temporal stores: keep xh+C resident in L3)
  #pragma unroll
  for (int cm = 0; cm < 8; ++cm) {
    const int rbase = row0 + wm * 128 + cm * 16 + q * 4;
    #pragma unroll
    for (int i2 = 0; i2 < 4; ++i2) {
      const size_t r = (size_t)(rbase + i2);
      float cp = Cin[r * DH + hd];
      float ig = sigf(acc[cm][0][i2] + bias[0]);
      float fg = sigf(acc[cm][1][i2] + bias[1]);
      float og = sigf(acc[cm][2][i2] + bias[2]);
      float gg = tanhf_(acc[cm][3][i2] + bias[3]);
      float cnew = fg * cp + ig * gg;
      float hnew = og * tanhf_(cnew);
      __builtin_nontemporal_store(cnew, &out[r * DH + hd]);
      __builtin_nontemporal_store(hnew, &out[(size_t)BROWS * DH + r * DH + hd]);
    }
  }
}

// ---- R3 fallback GEMM (fp32 A staging, proven) for 4MB <= ws < 68MB ----
__global__ __launch_bounds__(256, 3) void lstm_gemm(
    const float* __restrict__ x, const float* __restrict__ h,
    const __bf16* __restrict__ Wt, const float* __restrict__ bx,
    const float* __restrict__ bh, const float* __restrict__ Cin,
    float* __restrict__ out) {
  __shared__ __attribute__((aligned(16))) __bf16 Asf[BM * BK];
  __shared__ __attribute__((aligned(16))) __bf16 Bsf[BM * BK];
  const int tid  = threadIdx.x;
  const int lane = tid & 63;
  const int wave = tid >> 6;
  const int wm = wave >> 1, wn = wave & 1;
  const int jb   = blockIdx.x;
  const int row0 = blockIdx.y * BM;
  const __bf16* Bt = Wt + (size_t)jb * 128 * KTOT;
  f32x4 acc[4][4];
  #pragma unroll
  for (int a_ = 0; a_ < 4; ++a_)
    #pragma unroll
    for (int b_ = 0; b_ < 4; ++b_) acc[a_][b_] = (f32x4)0.0f;
  for (int k0 = 0; k0 < KTOT; k0 += BK) {
    const float* Aptr = (k0 < DH) ? (x + (size_t)row0 * DH + k0)
                                  : (h + (size_t)row0 * DH + (k0 - DH));
    bf16x8 ta[4], tb[4];
    #pragma unroll
    for (int it = 0; it < 4; ++it) {
      int lin = it * 256 + tid;
      int r = lin >> 3, c8 = lin & 7;
      const float* src = Aptr + r * DH + c8 * 8;
      float4 f0 = *(const float4*)src;
      float4 f1 = *(const float4*)(src + 4);
      bf16x8 v;
      v[0] = (__bf16)f0.x; v[1] = (__bf16)f0.y; v[2] = (__bf16)f0.z; v[3] = (__bf16)f0.w;
      v[4] = (__bf16)f1.x; v[5] = (__bf16)f1.y; v[6] = (__bf16)f1.z; v[7] = (__bf16)f1.w;
      ta[it] = v;
      tb[it] = *(const bf16x8*)(Bt + (size_t)r * KTOT + k0 + c8 * 8);
    }
    #pragma unroll
    for (int it = 0; it < 4; ++it) {
      int lin = it * 256 + tid;
      *(bf16x8*)&Asf[lin * 8] = ta[it];
      *(bf16x8*)&Bsf[lin * 8] = tb[it];
    }
    __syncthreads();
    #pragma unroll
    for (int ks = 0; ks < 2; ++ks) {
      const int ko = ks * 32 + (lane >> 4) * 8;
      bf16x8 af[4], bfr[4];
      #pragma unroll
      for (int cm = 0; cm < 4; ++cm)
        af[cm] = *(const bf16x8*)&Asf[(wm * 64 + cm * 16 + (lane & 15)) * BK + ko];
      #pragma unroll
      for (int cn = 0; cn < 4; ++cn)
        bfr[cn] = *(const bf16x8*)&Bsf[(wn * 64 + cn * 16 + (lane & 15)) * BK + ko];
      #pragma unroll
      for (int cm = 0; cm < 4; ++cm)
        #pragma unroll
        for (int cn = 0; cn < 4; ++cn)
          acc[cm][cn] = __builtin_amdgcn_mfma_f32_16x16x32_bf16(
              af[cm], bfr[cn], acc[cm][cn], 0, 0, 0);
    }
    __syncthreads();
  }
  const int hd = jb * 32 + wn * 16 + (lane & 15);
  float bias[4];
  #pragma unroll
  for (int g2 = 0; g2 < 4; ++g2) bias[g2] = bx[g2 * DH + hd] + bh[g2 * DH + hd];
  #pragma unroll
  for (int cm = 0; cm < 4; ++cm) {
    const int rbase = row0 + wm * 64 + cm * 16 + (lane >> 4) * 4;
    #pragma unroll
    for (int i2 = 0; i2 < 4; ++i2) {
      const size_t r = (size_t)(rbase + i2);
      float ig = sigf(acc[cm][0][i2] + bias[0]);
      float fg = sigf(acc[cm][1][i2] + bias[1]);
      float og = sigf(acc[cm][2][i2] + bias[2]);
      float gg = tanhf_(acc[cm][3][i2] + bias[3]);
      float cp = Cin[r * DH + hd];
      float cnew = fg * cp + ig * gg;
      float hnew = og * tanhf_(cnew);
      out[r * DH + hd] = cnew;
      out[(size_t)BROWS * DH + r * DH + hd] = hnew;
    }
  }
}

__global__ void lstm_naive(const float* __restrict__ x, const float* __restrict__ Cin,
                           const float* __restrict__ h, const float* __restrict__ Wx,
                           const float* __restrict__ bxp, const float* __restrict__ Wh,
                           const float* __restrict__ bhp, float* __restrict__ out) {
  int idx = blockIdx.x * 256 + threadIdx.x;
  int r = idx >> 9, hd = idx & 511;
  float z[4];
  #pragma unroll
  for (int g = 0; g < 4; ++g) z[g] = bxp[g * DH + hd] + bhp[g * DH + hd];
  for (int k = 0; k < DH; ++k) {
    float xv = x[(size_t)r * DH + k];
    #pragma unroll
    for (int g = 0; g < 4; ++g) z[g] += xv * Wx[k * 4 * DH + g * DH + hd];
  }
  for (int k = 0; k < DH; ++k) {
    float hv = h[(size_t)r * DH + k];
    #pragma unroll
    for (int g = 0; g < 4; ++g) z[g] += hv * Wh[k * 4 * DH + g * DH + hd];
  }
  float ig = sigf(z[0]), fg = sigf(z[1]), og = sigf(z[2]), gg = tanhf_(z[3]);
  float cp = Cin[(size_t)r * DH + hd];
  float cnew = fg * cp + ig * gg;
  float hnew = og * tanhf_(cnew);
  out[(size_t)r * DH + hd] = cnew;
  out[(size_t)BROWS * DH + (size_t)r * DH + hd] = hnew;
}

extern "C" void kernel_launch(void* const* d_in, const int* in_sizes, int n_in,
                              void* d_out, int out_size, void* d_ws, size_t ws_size,
                              hipStream_t stream) {
  const float* x  = (const float*)d_in[0];
  const float* Ci = (const float*)d_in[1];
  const float* h  = (const float*)d_in[2];
  const float* Wx = (const float*)d_in[3];
  const float* bx = (const float*)d_in[4];
  const float* Wh = (const float*)d_in[5];
  const float* bh = (const float*)d_in[6];
  float* out = (float*)d_out;

  const size_t wt_bytes = (size_t)2048 * KTOT * sizeof(__bf16);          // 4 MB
  const size_t xh_bytes = (size_t)BROWS * KTOT * sizeof(__bf16);         // 64 MB

  if (ws_size >= wt_bytes + xh_bytes) {
    __bf16* Wt = (__bf16*)d_ws;
    __bf16* xh = (__bf16*)((char*)d_ws + wt_bytes);
    pack_w<<<dim3(16, 16), dim3(256), 0, stream>>>(Wx, Wh, Wt);
    conv_xh<<<dim3((BROWS * KTOT / 8) / 256), dim3(256), 0, stream>>>(x, h, xh);
    lstm_gemm3<<<dim3(8, BROWS / 256), dim3(512), 0, stream>>>(xh, Wt, bx, bh, Ci, out);
  } else if (ws_size >= wt_bytes) {
    __bf16* Wt = (__bf16*)d_ws;
    pack_w<<<dim3(16, 16), dim3(256), 0, stream>>>(Wx, Wh, Wt);
    lstm_gemm<<<dim3(16, BROWS / BM), dim3(256), 0, stream>>>(x, h, Wt, bx, bh, Ci, out);
  } else {
    lstm_naive<<<dim3((BROWS * DH) / 256), dim3(256), 0, stream>>>(
        x, Ci, h, Wx, bx, Wh, bh, out);
  }
}

// Round 2
// 445.737 us; speedup vs baseline: 1.0518x; 1.0518x over previous
//
#include <hip/hip_runtime.h>
#include <stdint.h>

// LSTM cell, fp32 I/O: z = x@Wx + h@Wh + bx + bh (M=32768, N=2048, K=1024)
// fused with gate activations and C/h update. bf16 MFMA, fp32 accumulate.
// R6: ring-4 sub-tile pipeline (fixes R5's drain-0 anti-pattern, m218):
//     - BM=BN=256, 8 waves (2Mx4N); LDS = 4 sub-buffers of K-depth 32
//       (4 x (8KiB A + 8KiB B) x ... = 128 KiB total), ring-indexed
//     - while consuming sub-tile s, stage s+3 (depth-3 prefetch, ~6 phases
//       = ~1200 cyc of latency slack vs ~900 cyc HBM miss)
//     - end-of-subtile wait is COUNTED vmcnt(8): retires only s+1's 4
//       loads (issued 6 phases ago); never drains to 0 in the main loop
//     - 2 phases/sub-tile, 16 MFMA each, setprio(1) around MFMA (T5)
//     - sub-buffer swizzle: chunk position p = c ^ ((row>>1)&3) ->
//       per-16-lane-quarter 8 bank-groups x 2 lanes (conflict-free)

#define BROWS 32768
#define DH 512
#define KTOT 1024   // D_IN + D_H
#define BM 128
#define BK 64

typedef __attribute__((ext_vector_type(8))) __bf16 bf16x8;
typedef __attribute__((ext_vector_type(4))) float f32x4;
typedef __attribute__((address_space(1))) void gvoid;
typedef __attribute__((address_space(3))) void lvoid;

__device__ __forceinline__ void gl_lds16(const void* g, void* l) {
  __builtin_amdgcn_global_load_lds((gvoid*)g, (lvoid*)l, 16, 0, 0);
}

__device__ __forceinline__ float sigf(float v)  { return 1.0f / (1.0f + __expf(-v)); }
__device__ __forceinline__ float tanhf_(float v){ return 1.0f - 2.0f / (1.0f + __expf(2.0f * v)); }

// ---- pre-pass: xh[r][c] = bf16(c<512 ? x[r][c] : h[r][c-512]), coalesced ----
__global__ void conv_xh(const float* __restrict__ x, const float* __restrict__ h,
                        __bf16* __restrict__ xh) {
  int o = blockIdx.x * 256 + threadIdx.x;       // chunk of 8 elems
  int c = (o & 127) * 8;
  int r = o >> 7;
  const float* src = (c < DH) ? (x + (size_t)r * DH + c)
                              : (h + (size_t)r * DH + (c - DH));
  float4 f0 = *(const float4*)src;
  float4 f1 = *(const float4*)(src + 4);
  bf16x8 v;
  v[0] = (__bf16)f0.x; v[1] = (__bf16)f0.y; v[2] = (__bf16)f0.z; v[3] = (__bf16)f0.w;
  v[4] = (__bf16)f1.x; v[5] = (__bf16)f1.y; v[6] = (__bf16)f1.z; v[7] = (__bf16)f1.w;
  *(bf16x8*)(xh + (size_t)o * 8) = v;
}

// ---- pack: Wt[(jb*128+r)*1024+k], r = (hl>>4)*64 + g*16 + (hl&15),
//      n = g*512 + jb*32 + hl. Coalesced via LDS transpose tile.
//      For a 256-wide block q this reads as p = q*256 + w*64 + g*16 + l
//      <-> n = g*512 + q*64 + w*16 + l (gate g = cn, hd = q*64+w*16+l). ----
__global__ void pack_w(const float* __restrict__ Wx, const float* __restrict__ Wh,
                       __bf16* __restrict__ Wt) {
  __shared__ __bf16 T[128][72];                 // +8 pad
  const int jb = blockIdx.y;
  const int k0 = blockIdx.x * 64;
  const float* Wsrc = (k0 < DH) ? (Wx + (size_t)k0 * 4 * DH)
                                : (Wh + (size_t)(k0 - DH) * 4 * DH);
  const int t = threadIdx.x;
  const int s = t & 31, kr0 = t >> 5;           // 32 seg-threads x 8 k-rows
  const int g = s >> 3, q = s & 7;
  const int r0 = (q >> 2) * 64 + g * 16 + (q & 3) * 4;
  #pragma unroll
  for (int it = 0; it < 8; ++it) {
    int kr = it * 8 + kr0;
    float4 f = *(const float4*)(Wsrc + (size_t)kr * 4 * DH + g * DH + jb * 32 + q * 4);
    T[r0 + 0][kr] = (__bf16)f.x;
    T[r0 + 1][kr] = (__bf16)f.y;
    T[r0 + 2][kr] = (__bf16)f.z;
    T[r0 + 3][kr] = (__bf16)f.w;
  }
  __syncthreads();
  #pragma unroll
  for (int it = 0; it < 4; ++it) {
    int lin = it * 256 + t;                     // 0..1023
    int r = lin >> 3, k8 = lin & 7;
    bf16x8 v;
    #pragma unroll
    for (int j = 0; j < 8; ++j) v[j] = T[r][k8 * 8 + j];
    *(bf16x8*)(Wt + (size_t)(jb * 128 + r) * KTOT + k0 + k8 * 8) = v;
  }
}

// ==== main fused GEMM: 256x256, ring-4 sub-tile (K-depth 32) pipeline ====
#define SB __builtin_amdgcn_sched_barrier(0)
#define PH_PRE do { SB; __builtin_amdgcn_s_barrier(); \
  asm volatile("s_waitcnt lgkmcnt(0)" ::: "memory"); SB; } while (0)
#define PH_POST do { SB; __builtin_amdgcn_s_barrier(); SB; } while (0)

// stage one sub-tile's A (2 issues) / B (2 issues). dest chunk d holds
// source chunk c = (d&3) ^ ((row>>1)&3)  (row = d>>2), inverse of read swz.
#define STAGE_A2(B_, kk_) do { \
  _Pragma("unroll") \
  for (int it_ = 0; it_ < 2; ++it_) { \
    const int d_ = it_ * 512 + tid; \
    const int r_ = d_ >> 2; \
    const int c_ = (d_ & 3) ^ ((r_ >> 1) & 3); \
    gl_lds16(xh + (size_t)(row0 + r_) * KTOT + (kk_) + c_ * 8, \
             &As[B_][d_ * 8]); \
  } } while (0)

#define STAGE_B2(B_, kk_) do { \
  _Pragma("unroll") \
  for (int it_ = 0; it_ < 2; ++it_) { \
    const int d_ = it_ * 512 + tid; \
    const int r_ = d_ >> 2; \
    const int c_ = (d_ & 3) ^ ((r_ >> 1) & 3); \
    gl_lds16(Bt + (size_t)r_ * KTOT + (kk_) + c_ * 8, \
             &Bs[B_][d_ * 8]); \
  } } while (0)

// fragment reads: chunk q of row at swizzled position q ^ ((row>>1)&3)
#define DS_A4(B_, cmb_) do { \
  _Pragma("unroll") \
  for (int i_ = 0; i_ < 4; ++i_) { \
    const int row_ = wm * 128 + ((cmb_) + i_) * 16 + l15; \
    const int cp_ = q ^ ((row_ >> 1) & 3); \
    af[i_] = *(const bf16x8*)&As[B_][row_ * 32 + cp_ * 8]; \
  } } while (0)

#define DS_B4(B_) do { \
  _Pragma("unroll") \
  for (int i_ = 0; i_ < 4; ++i_) { \
    const int row_ = wn * 64 + i_ * 16 + l15; \
    const int cp_ = q ^ ((row_ >> 1) & 3); \
    bfr[i_] = *(const bf16x8*)&Bs[B_][row_ * 32 + cp_ * 8]; \
  } } while (0)

#define MFMA16(cmb_) do { \
  __builtin_amdgcn_s_setprio(1); \
  _Pragma("unroll") \
  for (int i_ = 0; i_ < 4; ++i_) \
    _Pragma("unroll") \
    for (int j_ = 0; j_ < 4; ++j_) \
      acc[(cmb_) + i_][j_] = __builtin_amdgcn_mfma_f32_16x16x32_bf16( \
          af[i_], bfr[j_], acc[(cmb_) + i_][j_], 0, 0, 0); \
  __builtin_amdgcn_s_setprio(0); \
} while (0)

// One sub-tile s (buffer B_ = s&3), 2 phases; stages sub-tile s+3 into
// buffer (B_+3)&3; ends with COUNTED vmcnt (WC_: "8" steady / "4" / "0"
// tail) + barrier -> sub-tile s+1's buffer is ready, deeper loads in flight.
#define SUBTILE(S_, B_, DOST_, WC_) do { \
  bf16x8 af[4], bfr[4]; \
  DS_B4(B_); DS_A4(B_, 0); \
  if (DOST_) STAGE_A2((B_ + 3) & 3, ((S_) + 3) * 32); \
  PH_PRE; MFMA16(0); PH_POST; \
  DS_A4(B_, 4); \
  if (DOST_) STAGE_B2((B_ + 3) & 3, ((S_) + 3) * 32); \
  PH_PRE; MFMA16(4); \
  SB; asm volatile("s_waitcnt vmcnt(" WC_ ")" ::: "memory"); \
  __builtin_amdgcn_s_barrier(); SB; \
} while (0)

#define SUBTILE_LAST(B_) do { \
  bf16x8 af[4], bfr[4]; \
  DS_B4(B_); DS_A4(B_, 0); \
  PH_PRE; MFMA16(0); PH_POST; \
  DS_A4(B_, 4); \
  PH_PRE; MFMA16(4); \
} while (0)

__global__ __launch_bounds__(512, 2) void lstm_gemm3(
    const __bf16* __restrict__ xh, const __bf16* __restrict__ Wt,
    const float* __restrict__ bx, const float* __restrict__ bh,
    const float* __restrict__ Cin, float* __restrict__ out) {
  // 4 ring sub-buffers, each 256 rows x 32 K-cols bf16 (16 KiB A + 16 KiB B)
  __shared__ __attribute__((aligned(16))) __bf16 As[4][256 * 32];
  __shared__ __attribute__((aligned(16))) __bf16 Bs[4][256 * 32];

  const int tid  = threadIdx.x;
  const int lane = tid & 63;
  const int wave = tid >> 6;
  const int wm = wave >> 2, wn = wave & 3;      // 2M x 4N
  const int q = lane >> 4, l15 = lane & 15;
  const int jb   = blockIdx.x;                  // 0..7 -> XCD-pinned (idx%8)
  const int row0 = blockIdx.y * 256;

  const __bf16* Bt = Wt + (size_t)jb * 256 * KTOT;

  // bias prefetch; gate g = cn, hd = jb*64 + wn*16 + l
  const int hd = jb * 64 + wn * 16 + l15;
  float bias[4];
  #pragma unroll
  for (int g = 0; g < 4; ++g) bias[g] = bx[g * DH + hd] + bh[g * DH + hd];

  f32x4 acc[8][4];
  #pragma unroll
  for (int a_ = 0; a_ < 8; ++a_)
    #pragma unroll
    for (int b_ = 0; b_ < 4; ++b_) acc[a_][b_] = (f32x4)0.0f;

  // prologue: stage sub-tiles 0,1,2 (12 issues); counted wait for sub-tile 0
  STAGE_A2(0, 0);  STAGE_B2(0, 0);
  STAGE_A2(1, 32); STAGE_B2(1, 32);
  STAGE_A2(2, 64); STAGE_B2(2, 64);
  SB; asm volatile("s_waitcnt vmcnt(8)" ::: "memory");
  __builtin_amdgcn_s_barrier(); SB;

  // 32 sub-tiles of K=32. Main loop s=0..27: stage s+3, wait vmcnt(8)
  // (retires exactly s+1's 4 loads, issued 6 phases earlier).
  for (int ss = 0; ss < 28; ss += 4) {
    SUBTILE(ss + 0, 0, 1, "8");
    SUBTILE(ss + 1, 1, 1, "8");
    SUBTILE(ss + 2, 2, 1, "8");
    SUBTILE(ss + 3, 3, 1, "8");
  }
  SUBTILE(28, 0, 1, "8");   // stages 31; outstanding after wait: 30,31
  SUBTILE(29, 1, 0, "4");   // outstanding after wait: 31
  SUBTILE(30, 2, 0, "0");   // drain 31 (last)
  SUBTILE_LAST(3);          // sub-tile 31, no stage, no wait

  // fused LSTM epilogue (non-temporal stores: keep xh+C resident in L3)
  #pragma unroll
  for (int cm = 0; cm < 8; ++cm) {
    const int rbase = row0 + wm * 128 + cm * 16 + q * 4;
    #pragma unroll
    for (int i2 = 0; i2 < 4; ++i2) {
      const size_t r = (size_t)(rbase + i2);
      float cp = Cin[r * DH + hd];
      float ig = sigf(acc[cm][0][i2] + bias[0]);
      float fg = sigf(acc[cm][1][i2] + bias[1]);
      float og = sigf(acc[cm][2][i2] + bias[2]);
      float gg = tanhf_(acc[cm][3][i2] + bias[3]);
      float cnew = fg * cp + ig * gg;
      float hnew = og * tanhf_(cnew);
      __builtin_nontemporal_store(cnew, &out[r * DH + hd]);
      __builtin_nontemporal_store(hnew, &out[(size_t)BROWS * DH + r * DH + hd]);
    }
  }
}

// ---- R3 fallback GEMM (fp32 A staging, proven) for 4MB <= ws < 68MB ----
__global__ __launch_bounds__(256, 3) void lstm_gemm(
    const float* __restrict__ x, const float* __restrict__ h,
    const __bf16* __restrict__ Wt, const float* __restrict__ bx,
    const float* __restrict__ bh, const float* __restrict__ Cin,
    float* __restrict__ out) {
  __shared__ __attribute__((aligned(16))) __bf16 Asf[BM * BK];
  __shared__ __attribute__((aligned(16))) __bf16 Bsf[BM * BK];
  const int tid  = threadIdx.x;
  const int lane = tid & 63;
  const int wave = tid >> 6;
  const int wm = wave >> 1, wn = wave & 1;
  const int jb   = blockIdx.x;
  const int row0 = blockIdx.y * BM;
  const __bf16* Bt = Wt + (size_t)jb * 128 * KTOT;
  f32x4 acc[4][4];
  #pragma unroll
  for (int a_ = 0; a_ < 4; ++a_)
    #pragma unroll
    for (int b_ = 0; b_ < 4; ++b_) acc[a_][b_] = (f32x4)0.0f;
  for (int k0 = 0; k0 < KTOT; k0 += BK) {
    const float* Aptr = (k0 < DH) ? (x + (size_t)row0 * DH + k0)
                                  : (h + (size_t)row0 * DH + (k0 - DH));
    bf16x8 ta[4], tb[4];
    #pragma unroll
    for (int it = 0; it < 4; ++it) {
      int lin = it * 256 + tid;
      int r = lin >> 3, c8 = lin & 7;
      const float* src = Aptr + r * DH + c8 * 8;
      float4 f0 = *(const float4*)src;
      float4 f1 = *(const float4*)(src + 4);
      bf16x8 v;
      v[0] = (__bf16)f0.x; v[1] = (__bf16)f0.y; v[2] = (__bf16)f0.z; v[3] = (__bf16)f0.w;
      v[4] = (__bf16)f1.x; v[5] = (__bf16)f1.y; v[6] = (__bf16)f1.z; v[7] = (__bf16)f1.w;
      ta[it] = v;
      tb[it] = *(const bf16x8*)(Bt + (size_t)r * KTOT + k0 + c8 * 8);
    }
    #pragma unroll
    for (int it = 0; it < 4; ++it) {
      int lin = it * 256 + tid;
      *(bf16x8*)&Asf[lin * 8] = ta[it];
      *(bf16x8*)&Bsf[lin * 8] = tb[it];
    }
    __syncthreads();
    #pragma unroll
    for (int ks = 0; ks < 2; ++ks) {
      const int ko = ks * 32 + (lane >> 4) * 8;
      bf16x8 af[4], bfr[4];
      #pragma unroll
      for (int cm = 0; cm < 4; ++cm)
        af[cm] = *(const bf16x8*)&Asf[(wm * 64 + cm * 16 + (lane & 15)) * BK + ko];
      #pragma unroll
      for (int cn = 0; cn < 4; ++cn)
        bfr[cn] = *(const bf16x8*)&Bsf[(wn * 64 + cn * 16 + (lane & 15)) * BK + ko];
      #pragma unroll
      for (int cm = 0; cm < 4; ++cm)
        #pragma unroll
        for (int cn = 0; cn < 4; ++cn)
          acc[cm][cn] = __builtin_amdgcn_mfma_f32_16x16x32_bf16(
              af[cm], bfr[cn], acc[cm][cn], 0, 0, 0);
    }
    __syncthreads();
  }
  const int hd = jb * 32 + wn * 16 + (lane & 15);
  float bias[4];
  #pragma unroll
  for (int g2 = 0; g2 < 4; ++g2) bias[g2] = bx[g2 * DH + hd] + bh[g2 * DH + hd];
  #pragma unroll
  for (int cm = 0; cm < 4; ++cm) {
    const int rbase = row0 + wm * 64 + cm * 16 + (lane >> 4) * 4;
    #pragma unroll
    for (int i2 = 0; i2 < 4; ++i2) {
      const size_t r = (size_t)(rbase + i2);
      float ig = sigf(acc[cm][0][i2] + bias[0]);
      float fg = sigf(acc[cm][1][i2] + bias[1]);
      float og = sigf(acc[cm][2][i2] + bias[2]);
      float gg = tanhf_(acc[cm][3][i2] + bias[3]);
      float cp = Cin[r * DH + hd];
      float cnew = fg * cp + ig * gg;
      float hnew = og * tanhf_(cnew);
      out[r * DH + hd] = cnew;
      out[(size_t)BROWS * DH + r * DH + hd] = hnew;
    }
  }
}

__global__ void lstm_naive(const float* __restrict__ x, const float* __restrict__ Cin,
                           const float* __restrict__ h, const float* __restrict__ Wx,
                           const float* __restrict__ bxp, const float* __restrict__ Wh,
                           const float* __restrict__ bhp, float* __restrict__ out) {
  int idx = blockIdx.x * 256 + threadIdx.x;
  int r = idx >> 9, hd = idx & 511;
  float z[4];
  #pragma unroll
  for (int g = 0; g < 4; ++g) z[g] = bxp[g * DH + hd] + bhp[g * DH + hd];
  for (int k = 0; k < DH; ++k) {
    float xv = x[(size_t)r * DH + k];
    #pragma unroll
    for (int g = 0; g < 4; ++g) z[g] += xv * Wx[k * 4 * DH + g * DH + hd];
  }
  for (int k = 0; k < DH; ++k) {
    float hv = h[(size_t)r * DH + k];
    #pragma unroll
    for (int g = 0; g < 4; ++g) z[g] += hv * Wh[k * 4 * DH + g * DH + hd];
  }
  float ig = sigf(z[0]), fg = sigf(z[1]), og = sigf(z[2]), gg = tanhf_(z[3]);
  float cp = Cin[(size_t)r * DH + hd];
  float cnew = fg * cp + ig * gg;
  float hnew = og * tanhf_(cnew);
  out[(size_t)r * DH + hd] = cnew;
  out[(size_t)BROWS * DH + (size_t)r * DH + hd] = hnew;
}

extern "C" void kernel_launch(void* const* d_in, const int* in_sizes, int n_in,
                              void* d_out, int out_size, void* d_ws, size_t ws_size,
                              hipStream_t stream) {
  const float* x  = (const float*)d_in[0];
  const float* Ci = (const float*)d_in[1];
  const float* h  = (const float*)d_in[2];
  const float* Wx = (const float*)d_in[3];
  const float* bx = (const float*)d_in[4];
  const float* Wh = (const float*)d_in[5];
  const float* bh = (const float*)d_in[6];
  float* out = (float*)d_out;

  const size_t wt_bytes = (size_t)2048 * KTOT * sizeof(__bf16);          // 4 MB
  const size_t xh_bytes = (size_t)BROWS * KTOT * sizeof(__bf16);         // 64 MB

  if (ws_size >= wt_bytes + xh_bytes) {
    __bf16* Wt = (__bf16*)d_ws;
    __bf16* xh = (__bf16*)((char*)d_ws + wt_bytes);
    pack_w<<<dim3(16, 16), dim3(256), 0, stream>>>(Wx, Wh, Wt);
    conv_xh<<<dim3((BROWS * KTOT / 8) / 256), dim3(256), 0, stream>>>(x, h, xh);
    lstm_gemm3<<<dim3(8, BROWS / 256), dim3(512), 0, stream>>>(xh, Wt, bx, bh, Ci, out);
  } else if (ws_size >= wt_bytes) {
    __bf16* Wt = (__bf16*)d_ws;
    pack_w<<<dim3(16, 16), dim3(256), 0, stream>>>(Wx, Wh, Wt);
    lstm_gemm<<<dim3(16, BROWS / BM), dim3(256), 0, stream>>>(x, h, Wt, bx, bh, Ci, out);
  } else {
    lstm_naive<<<dim3((BROWS * DH) / 256), dim3(256), 0, stream>>>(
        x, Ci, h, Wx, bx, Wh, bh, out);
  }
}